// Round 7
// baseline (726.113 us; speedup 1.0000x reference)
//
#include <hip/hip_runtime.h>
#include <hip/hip_bf16.h>

// Problem constants (TwoHopGATBlock)
#define BB 16
#define NN 1024
#define EE 32768
#define D_IN 33
#define HEADS 4
#define FF 32           // HEADS*OUT
#define EPSL 1e-5f
#define SLOPE 0.2f
#define CAP 96          // bucket capacity; actual max degree ~55 (fixed graph)
#define NBLK 1024       // grid size; 4 blocks/CU * 256 CUs -> all co-resident

typedef float v4f __attribute__((ext_vector_type(4)));

__device__ __forceinline__ float red32(float v) {
    v += __shfl_xor(v, 1);
    v += __shfl_xor(v, 2);
    v += __shfl_xor(v, 4);
    v += __shfl_xor(v, 8);
    v += __shfl_xor(v, 16);
    return v;
}
__device__ __forceinline__ float red8(float v) {
    v += __shfl_xor(v, 1);
    v += __shfl_xor(v, 2);
    v += __shfl_xor(v, 4);
    return v;
}
__device__ __forceinline__ void wb() { __builtin_amdgcn_wave_barrier(); }

// grid barrier: all NBLK blocks co-resident (launch_bounds guarantees 4/CU)
__device__ __forceinline__ void gridbar(int* bar) {
    __syncthreads();
    if (threadIdx.x == 0) {
        __threadfence();                    // release prior global writes
        atomicAdd(bar, 1);                  // device-scope by default
        while (__hip_atomic_load(bar, __ATOMIC_ACQUIRE,
                                 __HIP_MEMORY_SCOPE_AGENT) < NBLK)
            __builtin_amdgcn_s_sleep(16);
    }
    __syncthreads();
}

union SMem {
    struct {
        float sW1[D_IN * 32];
        float sW2[1024];
        float sWg[1024];
        float sb1[32], sb2[32], sg[32], sbt[32], sas[32], sad[32];
        float sh[8][34];
        float sx[8][33];
    } e;
    struct {
        float sW[1024];
        float sb[32], sas[32], sad[32];
        float sx[8][33];
        float salp[8][32];
        int ssrc[8][8];
    } g1;
    struct {
        float sRow[4][NN];      // one 4 KB row per wave
        float sb[32], sg[32], sbt[32];
        float salp[8][32];
        int ssrc[8][8];
    } p3;
};

__global__ __launch_bounds__(256, 4) void k_fused(
    const float* __restrict__ Hm, const int* __restrict__ ei,
    const float* __restrict__ W1, const float* __restrict__ b1,
    const float* __restrict__ W2, const float* __restrict__ b2,
    const float* __restrict__ lng, const float* __restrict__ lnb,
    const float* __restrict__ Wg1, const float* __restrict__ as1,
    const float* __restrict__ ad1, const float* __restrict__ bi1,
    const float* __restrict__ Wg2, const float* __restrict__ as2,
    const float* __restrict__ ad2, const float* __restrict__ bi2,
    const float* __restrict__ lnog, const float* __restrict__ lnob,
    int* cnt_in, int* cnt_out, int* bars, int* csr_b, int* out_b,
    float* xp1, float* als1, float* ald1, float* h1, float* xp2,
    float* als2, float2* aldinv, float* outH, float* A) {
    __shared__ SMem sm;
    int tid = threadIdx.x;
    int bid = blockIdx.x;
    int g = tid >> 5, j = tid & 31, h = j >> 3, t8 = j & 7;

    // ================= P0: embed (2 units) + bucket build =================
    for (int i = tid; i < D_IN * 32; i += 256) sm.e.sW1[i] = W1[i];
    for (int i = tid; i < 1024; i += 256) { sm.e.sW2[i] = W2[i]; sm.e.sWg[i] = Wg1[i]; }
    if (tid < 32) {
        sm.e.sb1[tid] = b1[tid]; sm.e.sb2[tid] = b2[tid];
        sm.e.sg[tid] = lng[tid]; sm.e.sbt[tid] = lnb[tid];
        sm.e.sas[tid] = as1[tid]; sm.e.sad[tid] = ad1[tid];
    }
    __syncthreads();
    for (int u = bid; u < 2048; u += NBLK) {
        int idx = u * 8 + g;   // b*N + n
        int base = idx * D_IN;
        for (int i = j; i < D_IN; i += 32) sm.e.sh[g][i] = Hm[base + i];
        wb();
        float acc = sm.e.sb1[j];
#pragma unroll
        for (int i = 0; i < D_IN; i++) acc += sm.e.sh[g][i] * sm.e.sW1[i * 32 + j];
        float x1 = fmaxf(acc, 0.f);
        sm.e.sx[g][j] = x1;
        wb();
        acc = sm.e.sb2[j];
#pragma unroll
        for (int i = 0; i < 32; i++) acc += sm.e.sx[g][i] * sm.e.sW2[i * 32 + j];
        float x2 = fmaxf(acc, 0.f);
        float mean = red32(x2) * (1.f / 32.f);
        float d0 = x2 - mean;
        float var = red32(d0 * d0) * (1.f / 32.f);
        float xn = d0 * rsqrtf(var + EPSL) * sm.e.sg[j] + sm.e.sbt[j];
        wb();
        sm.e.sx[g][j] = xn;
        wb();
        acc = 0.f;
#pragma unroll
        for (int i = 0; i < 32; i++) acc += sm.e.sx[g][i] * sm.e.sWg[i * 32 + j];
        xp1[idx * 32 + j] = acc;
        float ps = red8(acc * sm.e.sas[j]);
        float pd = red8(acc * sm.e.sad[j]);
        if (t8 == 0) {
            als1[idx * 4 + h] = ps;
            ald1[idx * 4 + h] = pd;
        }
        wb();
    }
    // bucket build: 32 edges per block (cnt_* zeroed by pre-kernel memset)
    if (tid < 32) {
        int e = bid * 32 + tid;
        int s = ei[e], d = ei[EE + e];
        int p = atomicAdd(&cnt_in[d], 1);
        csr_b[d * CAP + p] = s;
        int q = atomicAdd(&cnt_out[s], 1);
        out_b[s * CAP + q] = d;
    }
    gridbar(&bars[0]);

    // ================= P1: GAT layer 1 (2 units) =================
    for (int i = tid; i < 1024; i += 256) sm.g1.sW[i] = Wg2[i];
    if (tid < 32) { sm.g1.sb[tid] = bi1[tid]; sm.g1.sas[tid] = as2[tid]; sm.g1.sad[tid] = ad2[tid]; }
    __syncthreads();
    for (int u = bid; u < 2048; u += NBLK) {
        int idx = u * 8 + g;
        int b = idx >> 10, n = idx & 1023;
        int cnt = cnt_in[n];
        const int* row = csr_b + n * CAP;
        float aldh = ald1[idx * 4 + h];
        const float* alsb = als1 + b * NN * 4;
        const float* xpb = xp1 + b * NN * 32;
        float se = 0.f, acc = 0.f;
        for (int kb = 0; kb < cnt; kb += 8) {
            int k = kb + t8;
            float al = 0.f; int s = 0;
            if (k < cnt) {
                s = row[k];
                float av = alsb[s * 4 + h] + aldh;
                av = av > 0.f ? av : SLOPE * av;
                al = __expf(av);
            }
            se += al;
            sm.g1.salp[g][j] = al;
            if (h == 0) sm.g1.ssrc[g][t8] = s;
            wb();
#pragma unroll
            for (int t = 0; t < 8; t++)
                acc += sm.g1.salp[g][(h << 3) + t] * xpb[sm.g1.ssrc[g][t] * 32 + j];
            wb();
        }
        se = red8(se);
        float inv = se > 0.f ? 1.f / se : 0.f;
        acc *= inv;
        float hv = fmaxf(acc + sm.g1.sb[j], 0.f);
        h1[idx * 32 + j] = hv;
        sm.g1.sx[g][j] = hv;
        wb();
        float x2 = 0.f;
#pragma unroll
        for (int i = 0; i < 32; i++) x2 += sm.g1.sx[g][i] * sm.g1.sW[i * 32 + j];
        xp2[idx * 32 + j] = x2;
        float ps = red8(x2 * sm.g1.sas[j]);
        float pd = red8(x2 * sm.g1.sad[j]);
        if (t8 == 0) {
            als2[idx * 4 + h] = ps;                  // [b][n][4]
            aldinv[((b * 4 + h) << 10) + n].x = pd;  // [b][4][n]
        }
        wb();
    }
    gridbar(&bars[1]);

    // ================= P2: GAT layer 2 softmax denominators =================
    for (int u = bid; u < 2048; u += NBLK) {
        int idx = u * 8 + g;
        int b = idx >> 10, n = idx & 1023;
        int cnt = cnt_in[n];
        const int* row = csr_b + n * CAP;
        float aldh = aldinv[((b * 4 + h) << 10) + n].x;
        const float* alsb = als2 + b * NN * 4;
        float se = 0.f;
        for (int k = t8; k < cnt; k += 8) {
            int s = row[k];
            float av = alsb[s * 4 + h] + aldh;
            av = av > 0.f ? av : SLOPE * av;
            se += __expf(av);
        }
        se = red8(se);
        float inv = se > 0.f ? 1.f / se : 0.f;
        if (t8 == 0) aldinv[((b * 4 + h) << 10) + n].y = inv;
    }
    gridbar(&bars[2]);

    // ====== P3: gat2 aggregation + output LN, then rowA stream-out ======
    if (tid < 32) { sm.p3.sb[tid] = bi2[tid]; sm.p3.sg[tid] = lnog[tid]; sm.p3.sbt[tid] = lnob[tid]; }
    __syncthreads();
    for (int u = bid; u < 2048; u += NBLK) {
        int idx = u * 8 + g;
        int b = idx >> 10, n = idx & 1023;
        int cnt = cnt_in[n];
        const int* row = csr_b + n * CAP;
        float2 ai = aldinv[((b * 4 + h) << 10) + n];
        float aldh = ai.x, inv = ai.y;
        const float* alsb = als2 + b * NN * 4;
        const float* xpb = xp2 + b * NN * 32;
        float acc = 0.f;
        for (int kb = 0; kb < cnt; kb += 8) {
            int k = kb + t8;
            float al = 0.f; int s = 0;
            if (k < cnt) {
                s = row[k];
                float av = alsb[s * 4 + h] + aldh;
                av = av > 0.f ? av : SLOPE * av;
                al = __expf(av);
            }
            sm.p3.salp[g][j] = al;
            if (h == 0) sm.p3.ssrc[g][t8] = s;
            wb();
#pragma unroll
            for (int t = 0; t < 8; t++)
                acc += sm.p3.salp[g][(h << 3) + t] * xpb[sm.p3.ssrc[g][t] * 32 + j];
            wb();
        }
        acc *= inv;
        float y = h1[idx * 32 + j] + acc + sm.p3.sb[j];
        float mean = red32(y) * (1.f / 32.f);
        float d0 = y - mean;
        float var = red32(d0 * d0) * (1.f / 32.f);
        outH[idx * 32 + j] = d0 * rsqrtf(var + EPSL) * sm.p3.sg[j] + sm.p3.sbt[j];
        wb();
    }
    // rowA: 16 consecutive rows per wave; waves proceed independently
    {
        int wid = tid >> 6, lane = tid & 63;
        int w = bid * 4 + wid;
        v4f* row4 = (v4f*)&sm.p3.sRow[wid][0];
        for (int rr = 0; rr < 16; rr++) {
            int r = w * 16 + rr;             // (b*4+h)*1024 + src
            int bh = r >> 10, src = r & 1023;
            int b = bh >> 2, hh = bh & 3;
            float sS = als2[((b << 10) + src) * 4 + hh];
            const float2* aiv = aldinv + ((size_t)bh << 10);
            v4f z = {0.f, 0.f, 0.f, 0.f};
#pragma unroll
            for (int i = 0; i < 4; i++) row4[i * 64 + lane] = z;
            wb();
            int cnt = cnt_out[src];
            const int* erow = out_b + src * CAP;
            for (int p = lane; p < cnt; p += 64) {
                int d = erow[p];
                float2 ai = aiv[d];
                float lg = sS + ai.x;
                lg = lg > 0.f ? lg : SLOPE * lg;
                sm.p3.sRow[wid][d] = __expf(lg) * ai.y;
            }
            wb();
            float* orow = A + (size_t)bh * (NN * NN) + (size_t)src * NN;
#pragma unroll
            for (int i = 0; i < 4; i++)
                __builtin_nontemporal_store(row4[i * 64 + lane],
                                            (v4f*)(orow + 4 * (i * 64 + lane)));
            wb();
        }
    }
}

extern "C" void kernel_launch(void* const* d_in, const int* in_sizes, int n_in,
                              void* d_out, int out_size, void* d_ws, size_t ws_size,
                              hipStream_t stream) {
    const float* Hm  = (const float*)d_in[0];
    const int*   ei  = (const int*)d_in[1];
    const float* W1  = (const float*)d_in[2];
    const float* b1  = (const float*)d_in[3];
    const float* W2  = (const float*)d_in[4];
    const float* b2  = (const float*)d_in[5];
    const float* lneg = (const float*)d_in[6];
    const float* lneb = (const float*)d_in[7];
    const float* Wg1 = (const float*)d_in[8];
    const float* as1 = (const float*)d_in[9];
    const float* ad1 = (const float*)d_in[10];
    const float* bi1 = (const float*)d_in[11];
    const float* Wg2 = (const float*)d_in[12];
    const float* as2 = (const float*)d_in[13];
    const float* ad2 = (const float*)d_in[14];
    const float* bi2 = (const float*)d_in[15];
    const float* lnog = (const float*)d_in[16];
    const float* lnob = (const float*)d_in[17];

    float* outH = (float*)d_out;                 // [B,N,32]
    float* A    = outH + BB * NN * FF;           // [B,4,N,N]

    // workspace carve (memset zeroes cnt_in+cnt_out+bars = 2056 ints)
    int* cnt_in  = (int*)d_ws;             // 1024
    int* cnt_out = cnt_in + 1024;          // 1024
    int* bars    = cnt_out + 1024;         // 8 (3 used)
    int* csr_b   = bars + 8;               // 1024*96
    int* out_b   = csr_b + NN * CAP;       // 1024*96
    float* fb    = (float*)(out_b + NN * CAP);
    float* xp1    = fb;                    // 524288
    float* als1   = xp1 + BB * NN * FF;    // 65536
    float* ald1   = als1 + BB * NN * 4;    // 65536
    float* h1     = ald1 + BB * NN * 4;    // 524288
    float* xp2    = h1 + BB * NN * FF;     // 524288
    float* als2   = xp2 + BB * NN * FF;    // 65536
    float2* aldinv = (float2*)(als2 + BB * NN * 4);  // 65536 float2 ([b][4][n])

    (void)hipMemsetAsync(cnt_in, 0, 2056 * sizeof(int), stream);
    hipLaunchKernelGGL(k_fused, dim3(NBLK), dim3(256), 0, stream,
                       Hm, ei, W1, b1, W2, b2, lneg, lneb, Wg1, as1, ad1, bi1,
                       Wg2, as2, ad2, bi2, lnog, lnob,
                       cnt_in, cnt_out, bars, csr_b, out_b,
                       xp1, als1, ald1, h1, xp2, als2, aldinv, outH, A);
}

// Round 8
// 346.567 us; speedup vs baseline: 2.0952x; 2.0952x over previous
//
#include <hip/hip_runtime.h>
#include <hip/hip_bf16.h>

// Problem constants (TwoHopGATBlock)
#define BB 16
#define NN 1024
#define EE 32768
#define D_IN 33
#define HEADS 4
#define FF 32           // HEADS*OUT
#define EPSL 1e-5f
#define SLOPE 0.2f
#define CAP 96          // bucket capacity; actual max degree ~55 (fixed graph)

typedef float v4f __attribute__((ext_vector_type(4)));

__device__ __forceinline__ float red32(float v) {
    v += __shfl_xor(v, 1);
    v += __shfl_xor(v, 2);
    v += __shfl_xor(v, 4);
    v += __shfl_xor(v, 8);
    v += __shfl_xor(v, 16);
    return v;
}
__device__ __forceinline__ float red8(float v) {
    v += __shfl_xor(v, 1);
    v += __shfl_xor(v, 2);
    v += __shfl_xor(v, 4);
    return v;
}
__device__ __forceinline__ void wb() { __builtin_amdgcn_wave_barrier(); }

// ---- K1: embed MLP+LN+xp1+logits (blocks 0..2047); bucket build (2048..2175)
__global__ __launch_bounds__(256) void k_embed_bucket(
    const float* __restrict__ Hm, const float* __restrict__ W1,
    const float* __restrict__ b1, const float* __restrict__ W2,
    const float* __restrict__ b2, const float* __restrict__ lng,
    const float* __restrict__ lnb, const float* __restrict__ Wg1,
    const float* __restrict__ as1, const float* __restrict__ ad1,
    float* __restrict__ xp1, float* __restrict__ als1, float* __restrict__ ald1,
    const int* __restrict__ ei, int* __restrict__ cnt_in, int* __restrict__ cnt_out,
    int* __restrict__ csr_b, int* __restrict__ out_b) {
    int tid = threadIdx.x;
    if (blockIdx.x >= 2048) {
        int e = (blockIdx.x - 2048) * 256 + tid;   // 128 blocks * 256 = EE exactly
        int s = ei[e], d = ei[EE + e];
        int p = atomicAdd(&cnt_in[d], 1);
        csr_b[d * CAP + p] = s;
        int q = atomicAdd(&cnt_out[s], 1);
        out_b[s * CAP + q] = d;
        return;
    }
    __shared__ float sW1[D_IN * 32];
    __shared__ float sW2[1024];
    __shared__ float sWg[1024];
    __shared__ float sb1[32], sb2[32], sg[32], sbt[32], sas[32], sad[32];
    __shared__ float sh[8][34];
    __shared__ float sx[8][33];
    for (int i = tid; i < D_IN * 32; i += 256) sW1[i] = W1[i];
    for (int i = tid; i < 1024; i += 256) { sW2[i] = W2[i]; sWg[i] = Wg1[i]; }
    if (tid < 32) {
        sb1[tid] = b1[tid]; sb2[tid] = b2[tid];
        sg[tid] = lng[tid]; sbt[tid] = lnb[tid];
        sas[tid] = as1[tid]; sad[tid] = ad1[tid];
    }
    int g = tid >> 5, j = tid & 31;
    int idx = blockIdx.x * 8 + g;   // b*N + n
    __syncthreads();
    int base = idx * D_IN;
    for (int i = j; i < D_IN; i += 32) sh[g][i] = Hm[base + i];
    wb();
    float acc = sb1[j];
#pragma unroll
    for (int i = 0; i < D_IN; i++) acc += sh[g][i] * sW1[i * 32 + j];
    float x1 = fmaxf(acc, 0.f);
    sx[g][j] = x1;
    wb();
    acc = sb2[j];
#pragma unroll
    for (int i = 0; i < 32; i++) acc += sx[g][i] * sW2[i * 32 + j];
    float x2 = fmaxf(acc, 0.f);
    float mean = red32(x2) * (1.f / 32.f);
    float d0 = x2 - mean;
    float var = red32(d0 * d0) * (1.f / 32.f);
    float xn = d0 * rsqrtf(var + EPSL) * sg[j] + sbt[j];
    wb();
    sx[g][j] = xn;
    wb();
    acc = 0.f;
#pragma unroll
    for (int i = 0; i < 32; i++) acc += sx[g][i] * sWg[i * 32 + j];
    xp1[idx * 32 + j] = acc;
    float ps = red8(acc * sas[j]);
    float pd = red8(acc * sad[j]);
    if ((j & 7) == 0) {
        als1[idx * 4 + (j >> 3)] = ps;
        ald1[idx * 4 + (j >> 3)] = pd;
    }
}

// --------- K2: GAT layer 1, single sweep, pipelined chunks ---------------
__global__ __launch_bounds__(256) void k_gat1(
    const int* __restrict__ cnt_in, const int* __restrict__ csr_b,
    const float* __restrict__ xp1, const float* __restrict__ als1,
    const float* __restrict__ ald1, const float* __restrict__ bi1,
    const float* __restrict__ Wg2, const float* __restrict__ as2,
    const float* __restrict__ ad2, float* __restrict__ h1,
    float* __restrict__ xp2, float* __restrict__ als2,
    float2* __restrict__ aldinv) {
    __shared__ float sW[1024];
    __shared__ float sb[32], sas[32], sad[32];
    __shared__ float sx[8][33];
    __shared__ float salp[2][8][32];   // double buffer: no WAR barrier
    __shared__ int   ssrc[2][8][8];
    int tid = threadIdx.x;
    for (int i = tid; i < 1024; i += 256) sW[i] = Wg2[i];
    if (tid < 32) { sb[tid] = bi1[tid]; sas[tid] = as2[tid]; sad[tid] = ad2[tid]; }
    __syncthreads();
    int g = tid >> 5, j = tid & 31, h = j >> 3, t8 = j & 7;
    int idx = blockIdx.x * 8 + g;
    int b = idx >> 10, n = idx & 1023;
    int cnt = cnt_in[n];
    const int* row = csr_b + n * CAP;
    float aldh = ald1[idx * 4 + h];
    const float* alsb = als1 + b * NN * 4;
    const float* xpb = xp1 + b * NN * 32;
    float se = 0.f, acc = 0.f;
    // prologue: chunk 0 logits
    float al = 0.f; int s = 0;
    if (t8 < cnt) {
        s = row[t8];
        float av = alsb[s * 4 + h] + aldh;
        av = av > 0.f ? av : SLOPE * av;
        al = __expf(av);
    }
    int pb = 0;
    for (int kb = 0; kb < cnt; kb += 8, pb ^= 1) {
        se += al;
        salp[pb][g][j] = al;
        if (h == 0) ssrc[pb][g][t8] = s;
        wb();
        // prefetch next chunk's logit while gathering current
        al = 0.f; s = 0;
        int k = kb + 8 + t8;
        if (k < cnt) {
            s = row[k];
            float av = alsb[s * 4 + h] + aldh;
            av = av > 0.f ? av : SLOPE * av;
            al = __expf(av);
        }
#pragma unroll
        for (int t = 0; t < 8; t++)
            acc += salp[pb][g][(h << 3) + t] * xpb[ssrc[pb][g][t] * 32 + j];
    }
    se = red8(se);
    float inv = se > 0.f ? 1.f / se : 0.f;
    acc *= inv;
    float hv = fmaxf(acc + sb[j], 0.f);
    h1[idx * 32 + j] = hv;
    sx[g][j] = hv;
    wb();
    float x2 = 0.f;
#pragma unroll
    for (int i = 0; i < 32; i++) x2 += sx[g][i] * sW[i * 32 + j];
    xp2[idx * 32 + j] = x2;
    float ps = red8(x2 * sas[j]);
    float pd = red8(x2 * sad[j]);
    if (t8 == 0) {
        als2[idx * 4 + h] = ps;                      // [b][n][4] for gat2 gather
        aldinv[((b * 4 + h) << 10) + n].x = pd;      // [b][4][n] packed for rowA
    }
}

// --------- K3: GAT layer 2 single sweep + dinv + residual + output LN ----
__global__ __launch_bounds__(256) void k_gat2(
    const int* __restrict__ cnt_in, const int* __restrict__ csr_b,
    const float* __restrict__ xp2, const float* __restrict__ als2,
    float2* __restrict__ aldinv, const float* __restrict__ h1,
    const float* __restrict__ bi2, const float* __restrict__ lng,
    const float* __restrict__ lnb, float* __restrict__ outH) {
    __shared__ float sb[32], sg[32], sbt[32];
    __shared__ float salp[2][8][32];
    __shared__ int   ssrc[2][8][8];
    int tid = threadIdx.x;
    if (tid < 32) { sb[tid] = bi2[tid]; sg[tid] = lng[tid]; sbt[tid] = lnb[tid]; }
    __syncthreads();
    int g = tid >> 5, j = tid & 31, h = j >> 3, t8 = j & 7;
    int idx = blockIdx.x * 8 + g;
    int b = idx >> 10, n = idx & 1023;
    int cnt = cnt_in[n];
    const int* row = csr_b + n * CAP;
    float aldh = aldinv[((b * 4 + h) << 10) + n].x;
    const float* alsb = als2 + b * NN * 4;
    const float* xpb = xp2 + b * NN * 32;
    float se = 0.f, acc = 0.f;
    float al = 0.f; int s = 0;
    if (t8 < cnt) {
        s = row[t8];
        float av = alsb[s * 4 + h] + aldh;
        av = av > 0.f ? av : SLOPE * av;
        al = __expf(av);
    }
    int pb = 0;
    for (int kb = 0; kb < cnt; kb += 8, pb ^= 1) {
        se += al;
        salp[pb][g][j] = al;
        if (h == 0) ssrc[pb][g][t8] = s;
        wb();
        al = 0.f; s = 0;
        int k = kb + 8 + t8;
        if (k < cnt) {
            s = row[k];
            float av = alsb[s * 4 + h] + aldh;
            av = av > 0.f ? av : SLOPE * av;
            al = __expf(av);
        }
#pragma unroll
        for (int t = 0; t < 8; t++)
            acc += salp[pb][g][(h << 3) + t] * xpb[ssrc[pb][g][t] * 32 + j];
    }
    se = red8(se);
    float inv = se > 0.f ? 1.f / se : 0.f;
    if (t8 == 0) aldinv[((b * 4 + h) << 10) + n].y = inv;
    acc *= inv;
    float y = h1[idx * 32 + j] + acc + sb[j];
    float mean = red32(y) * (1.f / 32.f);
    float d0 = y - mean;
    float var = red32(d0 * d0) * (1.f / 32.f);
    outH[idx * 32 + j] = d0 * rsqrtf(var + EPSL) * sg[j] + sbt[j];
}

// --- K4: compose A rows (recompute alpha; packed aldinv), stream out -----
#define ROWS_PER_BLOCK 4
__global__ __launch_bounds__(256) void k_rowA(
    const int* __restrict__ cnt_out, const int* __restrict__ out_b,
    const float* __restrict__ als2, const float2* __restrict__ aldinv,
    float* __restrict__ A) {
    __shared__ float sRow[ROWS_PER_BLOCK][NN];
    int wid = threadIdx.x >> 6, lane = threadIdx.x & 63;
    int r = blockIdx.x * ROWS_PER_BLOCK + wid;   // (b*4+h)*1024 + src
    int bh = r >> 10, src = r & 1023;
    int b = bh >> 2, h = bh & 3;
    float sS = als2[((b << 10) + src) * 4 + h];
    const float2* aiv = aldinv + ((size_t)bh << 10);
    int cnt = cnt_out[src];
    const int* erow = out_b + src * CAP;
    v4f* row4 = (v4f*)&sRow[wid][0];
    v4f z = {0.f, 0.f, 0.f, 0.f};
#pragma unroll
    for (int i = 0; i < 4; i++) row4[i * 64 + lane] = z;
    wb();
    for (int p = lane; p < cnt; p += 64) {       // single iteration (cnt <= ~55)
        int d = erow[p];
        float2 ai = aiv[d];
        float lg = sS + ai.x;
        lg = lg > 0.f ? lg : SLOPE * lg;
        sRow[wid][d] = __expf(lg) * ai.y;
    }
    wb();
    float* orow = A + (size_t)bh * (NN * NN) + (size_t)src * NN;
#pragma unroll
    for (int i = 0; i < 4; i++)
        __builtin_nontemporal_store(row4[i * 64 + lane],
                                    (v4f*)(orow + 4 * (i * 64 + lane)));
}

extern "C" void kernel_launch(void* const* d_in, const int* in_sizes, int n_in,
                              void* d_out, int out_size, void* d_ws, size_t ws_size,
                              hipStream_t stream) {
    const float* Hm  = (const float*)d_in[0];
    const int*   ei  = (const int*)d_in[1];
    const float* W1  = (const float*)d_in[2];
    const float* b1  = (const float*)d_in[3];
    const float* W2  = (const float*)d_in[4];
    const float* b2  = (const float*)d_in[5];
    const float* lneg = (const float*)d_in[6];
    const float* lneb = (const float*)d_in[7];
    const float* Wg1 = (const float*)d_in[8];
    const float* as1 = (const float*)d_in[9];
    const float* ad1 = (const float*)d_in[10];
    const float* bi1 = (const float*)d_in[11];
    const float* Wg2 = (const float*)d_in[12];
    const float* as2 = (const float*)d_in[13];
    const float* ad2 = (const float*)d_in[14];
    const float* bi2 = (const float*)d_in[15];
    const float* lnog = (const float*)d_in[16];
    const float* lnob = (const float*)d_in[17];

    float* outH = (float*)d_out;                 // [B,N,32]
    float* A    = outH + BB * NN * FF;           // [B,4,N,N]

    // workspace carve
    int* cnt_in  = (int*)d_ws;             // 1024
    int* cnt_out = cnt_in + 1024;          // 1024  (memset zeroes both, 8 KB)
    int* csr_b   = cnt_out + 1024;         // 1024*96
    int* out_b   = csr_b + NN * CAP;       // 1024*96
    float* fb    = (float*)(out_b + NN * CAP);
    float* xp1    = fb;                    // 524288
    float* als1   = xp1 + BB * NN * FF;    // 65536
    float* ald1   = als1 + BB * NN * 4;    // 65536
    float* h1     = ald1 + BB * NN * 4;    // 524288
    float* xp2    = h1 + BB * NN * FF;     // 524288
    float* als2   = xp2 + BB * NN * FF;    // 65536
    float2* aldinv = (float2*)(als2 + BB * NN * 4);  // 65536 float2 ([b][4][n])

    (void)hipMemsetAsync(cnt_in, 0, 2 * NN * sizeof(int), stream);
    hipLaunchKernelGGL(k_embed_bucket, dim3(BB * NN / 8 + EE / 256), dim3(256), 0,
                       stream, Hm, W1, b1, W2, b2, lneg, lneb, Wg1, as1, ad1,
                       xp1, als1, ald1, ei, cnt_in, cnt_out, csr_b, out_b);
    hipLaunchKernelGGL(k_gat1, dim3(BB * NN / 8), dim3(256), 0, stream,
                       cnt_in, csr_b, xp1, als1, ald1, bi1, Wg2, as2, ad2,
                       h1, xp2, als2, aldinv);
    hipLaunchKernelGGL(k_gat2, dim3(BB * NN / 8), dim3(256), 0, stream,
                       cnt_in, csr_b, xp2, als2, aldinv, h1, bi2, lnog, lnob,
                       outH);
    hipLaunchKernelGGL(k_rowA, dim3(BB * HEADS * NN / ROWS_PER_BLOCK), dim3(256),
                       0, stream, cnt_out, out_b, als2, aldinv, A);
}